// Round 1
// baseline (564.820 us; speedup 1.0000x reference)
//
#include <hip/hip_runtime.h>
#include <hip/hip_bf16.h>

#define LL 2048
#define BB 2
#define DD 1024
#define HH 16
#define DKk 64

typedef __attribute__((ext_vector_type(8))) short s8v;
typedef __attribute__((ext_vector_type(8))) unsigned short u8v;
typedef __attribute__((ext_vector_type(4))) float f4v;

__device__ __forceinline__ ushort f2b(float f){
  union { __hip_bfloat16 h; ushort u; } c; c.h = __float2bfloat16(f); return c.u;
}
__device__ __forceinline__ float b2f(ushort u){
  union { __hip_bfloat16 h; ushort u; } c; c.u = u; return __bfloat162float(c.h);
}

// ---------------------------------------------------------------- pack x (transpose LBD->BLD + cast)
__global__ __launch_bounds__(256) void pack_x_kernel(
    const float* __restrict__ q, const float* __restrict__ k, const float* __restrict__ v,
    ushort* __restrict__ xq, ushort* __restrict__ xk, ushort* __restrict__ xv){
  int t = blockIdx.x*256 + threadIdx.x;       // 524288 threads, 8 elems each
  int m = t >> 7;                             // row in [B*L], b-major
  int dc = (t & 127) << 3;
  int b = m >> 11, l = m & (LL-1);
  size_t src = ((size_t)(l*BB + b) << 10) + dc;
  size_t dst = ((size_t)m << 10) + dc;
  #pragma unroll
  for (int i=0;i<3;++i){
    const float* ss = (i==0)?q:(i==1)?k:v;
    ushort* dd = (i==0)?xq:(i==1)?xk:xv;
    float4 a = *(const float4*)(ss+src);
    float4 bb = *(const float4*)(ss+src+4);
    u8v o;
    o[0]=f2b(a.x); o[1]=f2b(a.y); o[2]=f2b(a.z); o[3]=f2b(a.w);
    o[4]=f2b(bb.x);o[5]=f2b(bb.y);o[6]=f2b(bb.z);o[7]=f2b(bb.w);
    *(u8v*)(dd+dst) = o;
  }
}

// ---------------------------------------------------------------- pack weights (cast only)
__global__ __launch_bounds__(256) void pack_w_kernel(
    const float* __restrict__ Wq, const float* __restrict__ Wk,
    const float* __restrict__ Wv, const float* __restrict__ Wfc,
    ushort* __restrict__ wb){
  int t = blockIdx.x*256 + threadIdx.x;       // 524288 threads
  int which = t >> 17;
  size_t idx = (size_t)(t & 131071) << 3;
  const float* s = (which==0)?Wq:(which==1)?Wk:(which==2)?Wv:Wfc;
  float4 a = *(const float4*)(s+idx);
  float4 b4 = *(const float4*)(s+idx+4);
  u8v o;
  o[0]=f2b(a.x);o[1]=f2b(a.y);o[2]=f2b(a.z);o[3]=f2b(a.w);
  o[4]=f2b(b4.x);o[5]=f2b(b4.y);o[6]=f2b(b4.z);o[7]=f2b(b4.w);
  *(u8v*)(wb + ((size_t)which<<20) + idx) = o;
}

// ---------------------------------------------------------------- shared 128x128 bf16 GEMM body
// C[m][n] = sum_k A[m][k] * W[n][k]   (A:[4096][1024] bf16, W:[1024][1024] bf16)
// mode 0: out bf16 headed layout Qh/Kh[b][h][l][j] (scale applied)
// mode 2: out bf16 transposed    Vt[b][h][j][l]
// mode 3: out fp32 [m][n] = acc + resid[l*B+b][n]
__device__ __forceinline__ void gemm_body(
    const ushort* __restrict__ A, const ushort* __restrict__ W,
    ushort* __restrict__ outb, float* __restrict__ outf, const float* __restrict__ resid,
    int mode, float scale){
  __shared__ ushort As[4096];   // [128][32]
  __shared__ ushort Bs[4096];   // [128][32] (n-major)
  int tid = threadIdx.x;
  int w = tid>>6, lane = tid&63, lane15 = lane&15, g = lane>>4;
  int m0 = blockIdx.y<<7, n0 = blockIdx.x<<7;
  int wr = w>>1, wc = w&1;
  f4v z4 = {0.f,0.f,0.f,0.f};
  f4v acc[4][4];
  #pragma unroll
  for (int i=0;i<4;++i)
    #pragma unroll
    for (int j=0;j<4;++j) acc[i][j] = z4;

  int f0 = tid, f1 = 256 + tid;
  int r0 = f0>>2, c0 = (f0&3)<<3;
  int r1 = f1>>2, c1 = (f1&3)<<3;
  for (int k0=0; k0<1024; k0+=32){
    *(s8v*)&As[(r0<<5)+c0] = *(const s8v*)&A[((size_t)(m0+r0)<<10) + k0 + c0];
    *(s8v*)&As[(r1<<5)+c1] = *(const s8v*)&A[((size_t)(m0+r1)<<10) + k0 + c1];
    *(s8v*)&Bs[(r0<<5)+c0] = *(const s8v*)&W[((size_t)(n0+r0)<<10) + k0 + c0];
    *(s8v*)&Bs[(r1<<5)+c1] = *(const s8v*)&W[((size_t)(n0+r1)<<10) + k0 + c1];
    __syncthreads();
    s8v af[4], bf_[4];
    #pragma unroll
    for (int mi=0;mi<4;++mi) af[mi] = *(s8v*)&As[((wr*64 + mi*16 + lane15)<<5) + (g<<3)];
    #pragma unroll
    for (int ni=0;ni<4;++ni) bf_[ni] = *(s8v*)&Bs[((wc*64 + ni*16 + lane15)<<5) + (g<<3)];
    #pragma unroll
    for (int mi=0;mi<4;++mi)
      #pragma unroll
      for (int ni=0;ni<4;++ni)
        acc[mi][ni] = __builtin_amdgcn_mfma_f32_16x16x32_bf16(af[mi], bf_[ni], acc[mi][ni], 0,0,0);
    __syncthreads();
  }
  // epilogue: C layout col=lane&15, row=(lane>>4)*4+r
  #pragma unroll
  for (int mi=0;mi<4;++mi){
    #pragma unroll
    for (int ni=0;ni<4;++ni){
      int mbase = m0 + wr*64 + mi*16 + (g<<2);
      int ncol  = n0 + wc*64 + ni*16 + lane15;
      if (mode==0){
        int b=mbase>>11, h=ncol>>6, j=ncol&63;
        size_t o = (((size_t)(b*HH+h)*LL + (mbase&2047))<<6) + j;
        #pragma unroll
        for (int r=0;r<4;++r) outb[o + ((size_t)r<<6)] = f2b(acc[mi][ni][r]*scale);
      } else if (mode==2){
        int b=mbase>>11, h=ncol>>6, j=ncol&63;
        ushort4 pk = make_ushort4(f2b(acc[mi][ni][0]), f2b(acc[mi][ni][1]),
                                  f2b(acc[mi][ni][2]), f2b(acc[mi][ni][3]));
        *(ushort4*)&outb[(((size_t)(b*HH+h)*DKk + j)<<11) + (mbase&2047)] = pk;
      } else {
        int b=mbase>>11, l2=mbase&2047;
        #pragma unroll
        for (int r=0;r<4;++r)
          outf[((size_t)(mbase+r)<<10)+ncol] =
              acc[mi][ni][r] + resid[((size_t)((l2+r)*BB + b)<<10) + ncol];
      }
    }
  }
}

__global__ __launch_bounds__(256) void gemm_qkv_kernel(
    const ushort* __restrict__ xq, const ushort* __restrict__ xk, const ushort* __restrict__ xv,
    const ushort* __restrict__ wb, ushort* __restrict__ Qh, ushort* __restrict__ Kh, ushort* __restrict__ Vt){
  int z = blockIdx.z;
  const ushort* A = (z==0)?xq:(z==1)?xk:xv;
  const ushort* W = wb + ((size_t)z<<20);
  ushort* outb = (z==0)?Qh:(z==1)?Kh:Vt;
  int mode = (z==2)?2:0;
  float scale = (z==0)?0.125f:1.0f;
  gemm_body(A, W, outb, nullptr, nullptr, mode, scale);
}

__global__ __launch_bounds__(256) void gemm_fc_kernel(
    const ushort* __restrict__ ao, const ushort* __restrict__ wfc,
    const float* __restrict__ resid, float* __restrict__ fco){
  gemm_body(ao, wfc, nullptr, fco, resid, 3, 1.0f);
}

// ---------------------------------------------------------------- fused attention
// block = 16 Q-rows of one (b,h). S row tile lives in 64KB LDS (bf16, XOR-swizzled).
__global__ __launch_bounds__(256) void attn_kernel(
    const ushort* __restrict__ Qh, const ushort* __restrict__ Kh, const ushort* __restrict__ Vt,
    const float* __restrict__ sph, const int* __restrict__ mask,
    float* __restrict__ p_out, ushort* __restrict__ attn_out){
  extern __shared__ char smem[];            // 65536 B S-tile + 64 B redsum
  float* redsum = (float*)(smem + 65536);
  int tid = threadIdx.x, w = tid>>6, lane = tid&63, lane15 = lane&15, g = lane>>4;
  int bid = blockIdx.x;
  int qt = bid & 127, h = (bid>>7)&15, b = bid>>11;
  int q0 = qt<<4;
  size_t bh = (size_t)b*HH + h;

  // ---- P1: S = (Q/8) K^T  -> LDS bf16 (swizzled: byte ^= (row&7)<<4)
  const ushort* Qbase = Qh + ((bh*LL + q0 + lane15)<<6) + (g<<3);
  s8v qa0 = *(const s8v*)Qbase;
  s8v qa1 = *(const s8v*)(Qbase + 32);
  const ushort* Kbase = Kh + ((bh*LL + (w<<4) + lane15)<<6) + (g<<3);
  for (int it=0; it<32; ++it){
    const ushort* Kb = Kbase + (it<<12);    // advance 64 rows * 64 elems
    s8v kb0 = *(const s8v*)Kb;
    s8v kb1 = *(const s8v*)(Kb + 32);
    f4v c = {0.f,0.f,0.f,0.f};
    c = __builtin_amdgcn_mfma_f32_16x16x32_bf16(qa0, kb0, c, 0,0,0);
    c = __builtin_amdgcn_mfma_f32_16x16x32_bf16(qa1, kb1, c, 0,0,0);
    int colb = (((it<<6) + (w<<4)) + lane15) << 1;
    #pragma unroll
    for (int r=0;r<4;++r){
      int row = (g<<2)+r;
      *(ushort*)(smem + (row<<12) + (colb ^ ((row&7)<<4))) = f2b(c[r]);
    }
  }
  __syncthreads();

  // ---- P3a: modulate by sph & mask (coalesced 32B/lane), track row max
  int row = (w<<2) + g;                     // each (w,g) owns one of 16 rows
  int qrow = q0 + row;
  const float* sph_r = sph + ((bh*LL + qrow)<<11);
  const int*  msk_r  = mask + (((size_t)b*LL + qrow)<<11);
  int rswz = (row&7)<<4;
  char* Srow = smem + (row<<12);
  float mx = -3.0e38f;
  for (int c2=0;c2<16;++c2){
    int col = (lane15<<3) + (c2<<7);
    int boff = (col<<1) ^ rswz;
    s8v sv = *(s8v*)(Srow + boff);
    float4 p0 = *(const float4*)(sph_r + col);
    float4 p1 = *(const float4*)(sph_r + col + 4);
    int4 mk0 = *(const int4*)(msk_r + col);
    int4 mk1 = *(const int4*)(msk_r + col + 4);
    float sf[8];
    sf[0]=b2f((ushort)sv[0])*p0.x; sf[1]=b2f((ushort)sv[1])*p0.y;
    sf[2]=b2f((ushort)sv[2])*p0.z; sf[3]=b2f((ushort)sv[3])*p0.w;
    sf[4]=b2f((ushort)sv[4])*p1.x; sf[5]=b2f((ushort)sv[5])*p1.y;
    sf[6]=b2f((ushort)sv[6])*p1.z; sf[7]=b2f((ushort)sv[7])*p1.w;
    if (mk0.x==0) sf[0]=-1e9f;  if (mk0.y==0) sf[1]=-1e9f;
    if (mk0.z==0) sf[2]=-1e9f;  if (mk0.w==0) sf[3]=-1e9f;
    if (mk1.x==0) sf[4]=-1e9f;  if (mk1.y==0) sf[5]=-1e9f;
    if (mk1.z==0) sf[6]=-1e9f;  if (mk1.w==0) sf[7]=-1e9f;
    u8v ov;
    #pragma unroll
    for (int j=0;j<8;++j){ mx = fmaxf(mx, sf[j]); ov[j] = f2b(sf[j]); }
    *(u8v*)(Srow + boff) = ov;
  }
  #pragma unroll
  for (int off=1; off<16; off<<=1) mx = fmaxf(mx, __shfl_xor(mx, off, 64));

  // ---- P3b: e = exp(s - mx) (bf16 back to LDS), row sum
  float sum = 0.f;
  for (int c2=0;c2<16;++c2){
    int boff = (((lane15<<3)+(c2<<7))<<1) ^ rswz;
    s8v sv = *(s8v*)(Srow + boff);
    u8v ov;
    #pragma unroll
    for (int j=0;j<8;++j){
      float e = __expf(b2f((ushort)sv[j]) - mx);
      ushort ue = f2b(e);
      sum += b2f(ue);
      ov[j] = ue;
    }
    *(u8v*)(Srow + boff) = ov;
  }
  #pragma unroll
  for (int off=1; off<16; off<<=1) sum += __shfl_xor(sum, off, 64);
  if (lane15==0) redsum[row] = sum;
  __syncthreads();

  // ---- P5: p = e/sum -> d_out (coalesced float4 stores)
  float inv = 1.0f / sum;
  float* prow_p = p_out + ((bh*LL + qrow)<<11);
  for (int c2=0;c2<16;++c2){
    int col = (lane15<<3)+(c2<<7);
    s8v sv = *(s8v*)(Srow + ((col<<1) ^ rswz));
    float4 o0, o1;
    o0.x=b2f((ushort)sv[0])*inv; o0.y=b2f((ushort)sv[1])*inv;
    o0.z=b2f((ushort)sv[2])*inv; o0.w=b2f((ushort)sv[3])*inv;
    o1.x=b2f((ushort)sv[4])*inv; o1.y=b2f((ushort)sv[5])*inv;
    o1.z=b2f((ushort)sv[6])*inv; o1.w=b2f((ushort)sv[7])*inv;
    *(float4*)(prow_p + col) = o0;
    *(float4*)(prow_p + col + 4) = o1;
  }

  // ---- P6: O = (e V) / sum ; each wave owns a 16-wide d slice
  f4v oacc = {0.f,0.f,0.f,0.f};
  const ushort* Vb = Vt + ((bh*DKk + (w<<4) + lane15)<<11) + (g<<3);
  char* Sa = smem + (lane15<<12);
  int aswz = (lane15&7)<<4;
  for (int it=0; it<64; ++it){
    s8v pa = *(s8v*)(Sa + (((it<<6) + (g<<4)) ^ aswz));
    s8v vb = *(const s8v*)(Vb + (it<<5));
    oacc = __builtin_amdgcn_mfma_f32_16x16x32_bf16(pa, vb, oacc, 0,0,0);
  }
  #pragma unroll
  for (int r=0;r<4;++r){
    int qr = (g<<2)+r;
    float val = oacc[r] / redsum[qr];
    attn_out[((size_t)(b*LL + q0 + qr)<<10) + (h<<6) + (w<<4) + lane15] = f2b(val);
  }
}

// ---------------------------------------------------------------- LayerNorm + final transpose
__global__ __launch_bounds__(256) void ln_kernel(const float* __restrict__ fc,
    const float* __restrict__ gamma, const float* __restrict__ beta, float* __restrict__ out){
  __shared__ float rs[4], rq[4];
  int m = blockIdx.x, tid = threadIdx.x;
  int d0 = tid<<2;
  float4 x = *(const float4*)(fc + ((size_t)m<<10) + d0);
  float s = x.x+x.y+x.z+x.w;
  float sq = x.x*x.x+x.y*x.y+x.z*x.z+x.w*x.w;
  #pragma unroll
  for (int off=32; off; off>>=1){ s += __shfl_xor(s,off,64); sq += __shfl_xor(sq,off,64); }
  if ((tid&63)==0){ rs[tid>>6]=s; rq[tid>>6]=sq; }
  __syncthreads();
  float ts = rs[0]+rs[1]+rs[2]+rs[3];
  float tq = rq[0]+rq[1]+rq[2]+rq[3];
  float mu = ts*(1.0f/1024.0f);
  float var = tq*(1.0f/1024.0f) - mu*mu;
  float rr = rsqrtf(var + 1e-6f);
  float4 gm = *(const float4*)(gamma + d0);
  float4 bt = *(const float4*)(beta + d0);
  float4 y;
  y.x=(x.x-mu)*rr*gm.x+bt.x;
  y.y=(x.y-mu)*rr*gm.y+bt.y;
  y.z=(x.z-mu)*rr*gm.z+bt.z;
  y.w=(x.w-mu)*rr*gm.w+bt.w;
  int b=m>>11, l2=m&2047;
  *(float4*)(out + ((size_t)(l2*BB+b)<<10) + d0) = y;
}

// ---------------------------------------------------------------- launch
extern "C" void kernel_launch(void* const* d_in, const int* in_sizes, int n_in,
                              void* d_out, int out_size, void* d_ws, size_t ws_size,
                              hipStream_t stream){
  const float* q    = (const float*)d_in[0];
  const float* k    = (const float*)d_in[1];
  const float* v    = (const float*)d_in[2];
  const float* sph  = (const float*)d_in[3];
  const int*   mask = (const int*)d_in[4];
  const float* Wq   = (const float*)d_in[5];
  const float* Wk   = (const float*)d_in[6];
  const float* Wv   = (const float*)d_in[7];
  const float* Wfc  = (const float*)d_in[8];
  const float* gamma= (const float*)d_in[9];
  const float* beta = (const float*)d_in[10];
  float* outp  = (float*)d_out;
  float* p_out = outp + 4194304;            // L*B*D floats, then p_attn

  char* ws = (char*)d_ws;
  ushort* xq  = (ushort*)(ws);
  ushort* xk  = (ushort*)(ws + 8388608);
  ushort* xv  = (ushort*)(ws + 16777216);
  ushort* wb  = (ushort*)(ws + 25165824);   // 4 x 2MB bf16 weights
  ushort* Qh  = (ushort*)(ws + 33554432);
  ushort* Kh  = (ushort*)(ws + 41943040);
  ushort* Vt  = (ushort*)(ws + 50331648);
  ushort* ao  = (ushort*)(ws + 58720256);   // attn merged-head out bf16 [4096][1024]
  float*  fco = (float*)(ws + 67108864);    // fc + residual fp32 [4096][1024]

  pack_x_kernel<<<2048,256,0,stream>>>(q,k,v,xq,xk,xv);
  pack_w_kernel<<<2048,256,0,stream>>>(Wq,Wk,Wv,Wfc,wb);
  gemm_qkv_kernel<<<dim3(8,32,3),256,0,stream>>>(xq,xk,xv,wb,Qh,Kh,Vt);
  attn_kernel<<<4096,256,65600,stream>>>(Qh,Kh,Vt,sph,mask,p_out,ao);
  gemm_fc_kernel<<<dim3(8,32),256,0,stream>>>(ao, wb + 3145728, q, fco);
  ln_kernel<<<4096,256,0,stream>>>(fco, gamma, beta, outp);
}

// Round 2
// 553.647 us; speedup vs baseline: 1.0202x; 1.0202x over previous
//
#include <hip/hip_runtime.h>
#include <hip/hip_bf16.h>

#define LL 2048
#define BB 2
#define DD 1024
#define HH 16
#define DKk 64

typedef __attribute__((ext_vector_type(8))) short s8v;
typedef __attribute__((ext_vector_type(8))) unsigned short u8v;
typedef __attribute__((ext_vector_type(4))) float f4v;

__device__ __forceinline__ ushort f2b(float f){
  union { __hip_bfloat16 h; ushort u; } c; c.h = __float2bfloat16(f); return c.u;
}
__device__ __forceinline__ float b2f(ushort u){
  union { __hip_bfloat16 h; ushort u; } c; c.u = u; return __bfloat162float(c.h);
}

// ---------------------------------------------------------------- pack x (transpose LBD->BLD + cast)
__global__ __launch_bounds__(256) void pack_x_kernel(
    const float* __restrict__ q, const float* __restrict__ k, const float* __restrict__ v,
    ushort* __restrict__ xq, ushort* __restrict__ xk, ushort* __restrict__ xv){
  int t = blockIdx.x*256 + threadIdx.x;       // 524288 threads, 8 elems each
  int m = t >> 7;                             // row in [B*L], b-major
  int dc = (t & 127) << 3;
  int b = m >> 11, l = m & (LL-1);
  size_t src = ((size_t)(l*BB + b) << 10) + dc;
  size_t dst = ((size_t)m << 10) + dc;
  #pragma unroll
  for (int i=0;i<3;++i){
    const float* ss = (i==0)?q:(i==1)?k:v;
    ushort* dd = (i==0)?xq:(i==1)?xk:xv;
    float4 a = *(const float4*)(ss+src);
    float4 bb = *(const float4*)(ss+src+4);
    u8v o;
    o[0]=f2b(a.x); o[1]=f2b(a.y); o[2]=f2b(a.z); o[3]=f2b(a.w);
    o[4]=f2b(bb.x);o[5]=f2b(bb.y);o[6]=f2b(bb.z);o[7]=f2b(bb.w);
    *(u8v*)(dd+dst) = o;
  }
}

// ---------------------------------------------------------------- pack weights (cast only)
__global__ __launch_bounds__(256) void pack_w_kernel(
    const float* __restrict__ Wq, const float* __restrict__ Wk,
    const float* __restrict__ Wv, const float* __restrict__ Wfc,
    ushort* __restrict__ wb){
  int t = blockIdx.x*256 + threadIdx.x;       // 524288 threads
  int which = t >> 17;
  size_t idx = (size_t)(t & 131071) << 3;
  const float* s = (which==0)?Wq:(which==1)?Wk:(which==2)?Wv:Wfc;
  float4 a = *(const float4*)(s+idx);
  float4 b4 = *(const float4*)(s+idx+4);
  u8v o;
  o[0]=f2b(a.x);o[1]=f2b(a.y);o[2]=f2b(a.z);o[3]=f2b(a.w);
  o[4]=f2b(b4.x);o[5]=f2b(b4.y);o[6]=f2b(b4.z);o[7]=f2b(b4.w);
  *(u8v*)(wb + ((size_t)which<<20) + idx) = o;
}

// ---------------------------------------------------------------- shared 128x128 bf16 GEMM body
__device__ __forceinline__ void gemm_body(
    const ushort* __restrict__ A, const ushort* __restrict__ W,
    ushort* __restrict__ outb, float* __restrict__ outf, const float* __restrict__ resid,
    int mode, float scale){
  __shared__ ushort As[4096];   // [128][32]
  __shared__ ushort Bs[4096];   // [128][32] (n-major)
  int tid = threadIdx.x;
  int w = tid>>6, lane = tid&63, lane15 = lane&15, g = lane>>4;
  int m0 = blockIdx.y<<7, n0 = blockIdx.x<<7;
  int wr = w>>1, wc = w&1;
  f4v z4 = {0.f,0.f,0.f,0.f};
  f4v acc[4][4];
  #pragma unroll
  for (int i=0;i<4;++i)
    #pragma unroll
    for (int j=0;j<4;++j) acc[i][j] = z4;

  int f0 = tid, f1 = 256 + tid;
  int r0 = f0>>2, c0 = (f0&3)<<3;
  int r1 = f1>>2, c1 = (f1&3)<<3;
  for (int k0=0; k0<1024; k0+=32){
    *(s8v*)&As[(r0<<5)+c0] = *(const s8v*)&A[((size_t)(m0+r0)<<10) + k0 + c0];
    *(s8v*)&As[(r1<<5)+c1] = *(const s8v*)&A[((size_t)(m0+r1)<<10) + k0 + c1];
    *(s8v*)&Bs[(r0<<5)+c0] = *(const s8v*)&W[((size_t)(n0+r0)<<10) + k0 + c0];
    *(s8v*)&Bs[(r1<<5)+c1] = *(const s8v*)&W[((size_t)(n0+r1)<<10) + k0 + c1];
    __syncthreads();
    s8v af[4], bf_[4];
    #pragma unroll
    for (int mi=0;mi<4;++mi) af[mi] = *(s8v*)&As[((wr*64 + mi*16 + lane15)<<5) + (g<<3)];
    #pragma unroll
    for (int ni=0;ni<4;++ni) bf_[ni] = *(s8v*)&Bs[((wc*64 + ni*16 + lane15)<<5) + (g<<3)];
    #pragma unroll
    for (int mi=0;mi<4;++mi)
      #pragma unroll
      for (int ni=0;ni<4;++ni)
        acc[mi][ni] = __builtin_amdgcn_mfma_f32_16x16x32_bf16(af[mi], bf_[ni], acc[mi][ni], 0,0,0);
    __syncthreads();
  }
  #pragma unroll
  for (int mi=0;mi<4;++mi){
    #pragma unroll
    for (int ni=0;ni<4;++ni){
      int mbase = m0 + wr*64 + mi*16 + (g<<2);
      int ncol  = n0 + wc*64 + ni*16 + lane15;
      if (mode==0){
        int b=mbase>>11, h=ncol>>6, j=ncol&63;
        size_t o = (((size_t)(b*HH+h)*LL + (mbase&2047))<<6) + j;
        #pragma unroll
        for (int r=0;r<4;++r) outb[o + ((size_t)r<<6)] = f2b(acc[mi][ni][r]*scale);
      } else if (mode==2){
        int b=mbase>>11, h=ncol>>6, j=ncol&63;
        ushort4 pk = make_ushort4(f2b(acc[mi][ni][0]), f2b(acc[mi][ni][1]),
                                  f2b(acc[mi][ni][2]), f2b(acc[mi][ni][3]));
        *(ushort4*)&outb[(((size_t)(b*HH+h)*DKk + j)<<11) + (mbase&2047)] = pk;
      } else {
        int b=mbase>>11, l2=mbase&2047;
        #pragma unroll
        for (int r=0;r<4;++r)
          outf[((size_t)(mbase+r)<<10)+ncol] =
              acc[mi][ni][r] + resid[((size_t)((l2+r)*BB + b)<<10) + ncol];
      }
    }
  }
}

__global__ __launch_bounds__(256) void gemm_qkv_kernel(
    const ushort* __restrict__ xq, const ushort* __restrict__ xk, const ushort* __restrict__ xv,
    const ushort* __restrict__ wb, ushort* __restrict__ Qh, ushort* __restrict__ Kh, ushort* __restrict__ Vt){
  int z = blockIdx.z;
  const ushort* A = (z==0)?xq:(z==1)?xk:xv;
  const ushort* W = wb + ((size_t)z<<20);
  ushort* outb = (z==0)?Qh:(z==1)?Kh:Vt;
  int mode = (z==2)?2:0;
  float scale = (z==0)?0.125f:1.0f;
  gemm_body(A, W, outb, nullptr, nullptr, mode, scale);
}

__global__ __launch_bounds__(256) void gemm_fc_kernel(
    const ushort* __restrict__ ao, const ushort* __restrict__ wfc,
    const float* __restrict__ resid, float* __restrict__ fco){
  gemm_body(ao, wfc, nullptr, fco, resid, 3, 1.0f);
}

// ---------------------------------------------------------------- fused attention
// block = 16 Q-rows of one (b,h), 1024 threads (16 waves). S-tile 64KB bf16 LDS,
// XOR-swizzled (byte ^= (row&7)<<4). No max pass: logits bounded, exp in fp32;
// masked entries -> e = 0 exactly (== exp(-1e9)).
__global__ __launch_bounds__(1024) void attn_kernel(
    const ushort* __restrict__ Qh, const ushort* __restrict__ Kh, const ushort* __restrict__ Vt,
    const float* __restrict__ sph, const int* __restrict__ mask,
    float* __restrict__ p_out, ushort* __restrict__ attn_out){
  extern __shared__ char smem[];            // 65536 S + 13056 partials + 64 redsum
  float* pbuf   = (float*)(smem + 65536);   // [3][16][68-padded]
  float* redsum = (float*)(smem + 65536 + 13056);
  int tid = threadIdx.x, w = tid>>6, lane = tid&63, lane15 = lane&15, g = lane>>4;
  int bid = blockIdx.x;
  int qt = bid & 127, h = (bid>>7)&15, b = bid>>11;
  int q0 = qt<<4;
  size_t bh = (size_t)b*HH + h;

  // ---- P1: S = (Q/8) K^T -> LDS bf16 swizzled. wave w owns col chunks w*8..w*8+7.
  const ushort* Qbase = Qh + ((bh*LL + q0 + lane15)<<6) + (g<<3);
  s8v qa0 = *(const s8v*)Qbase;
  s8v qa1 = *(const s8v*)(Qbase + 32);
  #pragma unroll
  for (int cc=0; cc<8; ++cc){
    int c = (w<<3) + cc;                    // 16-col chunk index, 0..127
    const ushort* Kb = Kh + ((bh*LL + (c<<4) + lane15)<<6) + (g<<3);
    s8v kb0 = *(const s8v*)Kb;
    s8v kb1 = *(const s8v*)(Kb + 32);
    f4v cacc = {0.f,0.f,0.f,0.f};
    cacc = __builtin_amdgcn_mfma_f32_16x16x32_bf16(qa0, kb0, cacc, 0,0,0);
    cacc = __builtin_amdgcn_mfma_f32_16x16x32_bf16(qa1, kb1, cacc, 0,0,0);
    int colb = ((c<<4) + lane15) << 1;
    #pragma unroll
    for (int r=0;r<4;++r){
      int row = (g<<2)+r;
      *(ushort*)(smem + (row<<12) + (colb ^ ((row&7)<<4))) = f2b(cacc[r]);
    }
  }
  __syncthreads();

  // ---- P2: wave w owns q-row w. e = mask ? exp(S*sph) : 0 -> LDS bf16; row sum.
  int row = w;
  int qrow = q0 + row;
  const float* sph_r = sph + ((bh*LL + qrow)<<11);
  const int*  msk_r  = mask + (((size_t)b*LL + qrow)<<11);
  int rswz = (row&7)<<4;
  char* Srow = smem + (row<<12);
  float sum = 0.f;
  #pragma unroll
  for (int c2=0;c2<4;++c2){
    int col = (lane<<3) + (c2<<9);
    int boff = (col<<1) ^ rswz;
    s8v sv = *(s8v*)(Srow + boff);
    float4 p0 = *(const float4*)(sph_r + col);
    float4 p1 = *(const float4*)(sph_r + col + 4);
    int4 mk0 = *(const int4*)(msk_r + col);
    int4 mk1 = *(const int4*)(msk_r + col + 4);
    float e[8];
    e[0] = mk0.x ? __expf(b2f((ushort)sv[0])*p0.x) : 0.f;
    e[1] = mk0.y ? __expf(b2f((ushort)sv[1])*p0.y) : 0.f;
    e[2] = mk0.z ? __expf(b2f((ushort)sv[2])*p0.z) : 0.f;
    e[3] = mk0.w ? __expf(b2f((ushort)sv[3])*p0.w) : 0.f;
    e[4] = mk1.x ? __expf(b2f((ushort)sv[4])*p1.x) : 0.f;
    e[5] = mk1.y ? __expf(b2f((ushort)sv[5])*p1.y) : 0.f;
    e[6] = mk1.z ? __expf(b2f((ushort)sv[6])*p1.z) : 0.f;
    e[7] = mk1.w ? __expf(b2f((ushort)sv[7])*p1.w) : 0.f;
    u8v ov;
    #pragma unroll
    for (int j=0;j<8;++j){ ushort ue = f2b(e[j]); sum += b2f(ue); ov[j] = ue; }
    *(u8v*)(Srow + boff) = ov;
  }
  #pragma unroll
  for (int off=1; off<64; off<<=1) sum += __shfl_xor(sum, off, 64);
  if (lane==0) redsum[row] = sum;

  // ---- P3: normalized p -> global (reads only own row; no barrier needed yet)
  float inv = 1.0f / sum;
  float* prow_p = p_out + ((bh*LL + qrow)<<11);
  #pragma unroll
  for (int c2=0;c2<4;++c2){
    int col = (lane<<3) + (c2<<9);
    s8v sv = *(s8v*)(Srow + ((col<<1) ^ rswz));
    float4 o0, o1;
    o0.x=b2f((ushort)sv[0])*inv; o0.y=b2f((ushort)sv[1])*inv;
    o0.z=b2f((ushort)sv[2])*inv; o0.w=b2f((ushort)sv[3])*inv;
    o1.x=b2f((ushort)sv[4])*inv; o1.y=b2f((ushort)sv[5])*inv;
    o1.z=b2f((ushort)sv[6])*inv; o1.w=b2f((ushort)sv[7])*inv;
    *(float4*)(prow_p + col) = o0;
    *(float4*)(prow_p + col + 4) = o1;
  }
  __syncthreads();

  // ---- P4: O = (e V)/sum. wave w: d-slice ds=w&3, k-quarter kq=w>>2 (512 k each).
  int ds = w & 3, kq = w >> 2;
  f4v oacc = {0.f,0.f,0.f,0.f};
  const ushort* Vb = Vt + ((bh*DKk + (ds<<4) + lane15)<<11) + (kq<<9) + (g<<3);
  char* Sa = smem + (lane15<<12);
  int aswz = (lane15&7)<<4;
  #pragma unroll
  for (int it=0; it<16; ++it){
    s8v pa = *(s8v*)(Sa + (((kq<<10) + (it<<6) + (g<<4)) ^ aswz));
    s8v vb = *(const s8v*)(Vb + (it<<5));
    oacc = __builtin_amdgcn_mfma_f32_16x16x32_bf16(pa, vb, oacc, 0,0,0);
  }
  if (kq){
    float* pp = pbuf + ((kq-1)*1088);
    #pragma unroll
    for (int r=0;r<4;++r) pp[((g<<2)+r)*68 + (ds<<4) + lane15] = oacc[r];
  }
  __syncthreads();
  if (kq==0){
    #pragma unroll
    for (int p=0;p<3;++p){
      float* pp = pbuf + p*1088;
      #pragma unroll
      for (int r=0;r<4;++r) oacc[r] += pp[((g<<2)+r)*68 + (ds<<4) + lane15];
    }
    #pragma unroll
    for (int r=0;r<4;++r){
      int qr = (g<<2)+r;
      float val = oacc[r] / redsum[qr];
      attn_out[((size_t)(b*LL + q0 + qr)<<10) + (h<<6) + (ds<<4) + lane15] = f2b(val);
    }
  }
}

// ---------------------------------------------------------------- LayerNorm + final transpose
__global__ __launch_bounds__(256) void ln_kernel(const float* __restrict__ fc,
    const float* __restrict__ gamma, const float* __restrict__ beta, float* __restrict__ out){
  __shared__ float rs[4], rq[4];
  int m = blockIdx.x, tid = threadIdx.x;
  int d0 = tid<<2;
  float4 x = *(const float4*)(fc + ((size_t)m<<10) + d0);
  float s = x.x+x.y+x.z+x.w;
  float sq = x.x*x.x+x.y*x.y+x.z*x.z+x.w*x.w;
  #pragma unroll
  for (int off=32; off; off>>=1){ s += __shfl_xor(s,off,64); sq += __shfl_xor(sq,off,64); }
  if ((tid&63)==0){ rs[tid>>6]=s; rq[tid>>6]=sq; }
  __syncthreads();
  float ts = rs[0]+rs[1]+rs[2]+rs[3];
  float tq = rq[0]+rq[1]+rq[2]+rq[3];
  float mu = ts*(1.0f/1024.0f);
  float var = tq*(1.0f/1024.0f) - mu*mu;
  float rr = rsqrtf(var + 1e-6f);
  float4 gm = *(const float4*)(gamma + d0);
  float4 bt = *(const float4*)(beta + d0);
  float4 y;
  y.x=(x.x-mu)*rr*gm.x+bt.x;
  y.y=(x.y-mu)*rr*gm.y+bt.y;
  y.z=(x.z-mu)*rr*gm.z+bt.z;
  y.w=(x.w-mu)*rr*gm.w+bt.w;
  int b=m>>11, l2=m&2047;
  *(float4*)(out + ((size_t)(l2*BB+b)<<10) + d0) = y;
}

// ---------------------------------------------------------------- launch
extern "C" void kernel_launch(void* const* d_in, const int* in_sizes, int n_in,
                              void* d_out, int out_size, void* d_ws, size_t ws_size,
                              hipStream_t stream){
  const float* q    = (const float*)d_in[0];
  const float* k    = (const float*)d_in[1];
  const float* v    = (const float*)d_in[2];
  const float* sph  = (const float*)d_in[3];
  const int*   mask = (const int*)d_in[4];
  const float* Wq   = (const float*)d_in[5];
  const float* Wk   = (const float*)d_in[6];
  const float* Wv   = (const float*)d_in[7];
  const float* Wfc  = (const float*)d_in[8];
  const float* gamma= (const float*)d_in[9];
  const float* beta = (const float*)d_in[10];
  float* outp  = (float*)d_out;
  float* p_out = outp + 4194304;            // L*B*D floats, then p_attn

  char* ws = (char*)d_ws;
  ushort* xq  = (ushort*)(ws);
  ushort* xk  = (ushort*)(ws + 8388608);
  ushort* xv  = (ushort*)(ws + 16777216);
  ushort* wb  = (ushort*)(ws + 25165824);   // 4 x 2MB bf16 weights
  ushort* Qh  = (ushort*)(ws + 33554432);
  ushort* Kh  = (ushort*)(ws + 41943040);
  ushort* Vt  = (ushort*)(ws + 50331648);
  ushort* ao  = (ushort*)(ws + 58720256);   // attn merged-head out bf16 [4096][1024]
  float*  fco = (float*)(ws + 67108864);    // fc + residual fp32 [4096][1024]

  pack_x_kernel<<<2048,256,0,stream>>>(q,k,v,xq,xk,xv);
  pack_w_kernel<<<2048,256,0,stream>>>(Wq,Wk,Wv,Wfc,wb);
  gemm_qkv_kernel<<<dim3(8,32,3),256,0,stream>>>(xq,xk,xv,wb,Qh,Kh,Vt);
  attn_kernel<<<4096,1024,78784,stream>>>(Qh,Kh,Vt,sph,mask,p_out,ao);
  gemm_fc_kernel<<<dim3(8,32),256,0,stream>>>(ao, wb + 3145728, q, fco);
  ln_kernel<<<4096,256,0,stream>>>(fco, gamma, beta, outp);
}

// Round 3
// 517.439 us; speedup vs baseline: 1.0916x; 1.0700x over previous
//
#include <hip/hip_runtime.h>
#include <hip/hip_bf16.h>

#define LL 2048
#define BB 2
#define DD 1024
#define HH 16
#define DKk 64

typedef __attribute__((ext_vector_type(8))) short s8v;
typedef __attribute__((ext_vector_type(8))) unsigned short u8v;
typedef __attribute__((ext_vector_type(4))) float f4v;

__device__ __forceinline__ ushort f2b(float f){
  union { __hip_bfloat16 h; ushort u; } c; c.h = __float2bfloat16(f); return c.u;
}
__device__ __forceinline__ float b2f(ushort u){
  union { __hip_bfloat16 h; ushort u; } c; c.u = u; return __bfloat162float(c.h);
}
__device__ __forceinline__ f4v nt4(const float* p){ return __builtin_nontemporal_load((const f4v*)p); }
__device__ __forceinline__ void nts4(float* p, f4v v){ __builtin_nontemporal_store(v, (f4v*)p); }

// ---------------------------------------------------------------- pack x (transpose LBD->BLD + cast)
__global__ __launch_bounds__(256) void pack_x_kernel(
    const float* __restrict__ q, const float* __restrict__ k, const float* __restrict__ v,
    ushort* __restrict__ xq, ushort* __restrict__ xk, ushort* __restrict__ xv){
  int t = blockIdx.x*256 + threadIdx.x;       // 524288 threads, 8 elems each
  int m = t >> 7;                             // row in [B*L], b-major
  int dc = (t & 127) << 3;
  int b = m >> 11, l = m & (LL-1);
  size_t src = ((size_t)(l*BB + b) << 10) + dc;
  size_t dst = ((size_t)m << 10) + dc;
  #pragma unroll
  for (int i=0;i<3;++i){
    const float* ss = (i==0)?q:(i==1)?k:v;
    ushort* dd = (i==0)?xq:(i==1)?xk:xv;
    float4 a = *(const float4*)(ss+src);
    float4 bb = *(const float4*)(ss+src+4);
    u8v o;
    o[0]=f2b(a.x); o[1]=f2b(a.y); o[2]=f2b(a.z); o[3]=f2b(a.w);
    o[4]=f2b(bb.x);o[5]=f2b(bb.y);o[6]=f2b(bb.z);o[7]=f2b(bb.w);
    *(u8v*)(dd+dst) = o;
  }
}

// ---------------------------------------------------------------- pack weights (cast only)
__global__ __launch_bounds__(256) void pack_w_kernel(
    const float* __restrict__ Wq, const float* __restrict__ Wk,
    const float* __restrict__ Wv, const float* __restrict__ Wfc,
    ushort* __restrict__ wb){
  int t = blockIdx.x*256 + threadIdx.x;       // 524288 threads
  int which = t >> 17;
  size_t idx = (size_t)(t & 131071) << 3;
  const float* s = (which==0)?Wq:(which==1)?Wk:(which==2)?Wv:Wfc;
  float4 a = *(const float4*)(s+idx);
  float4 b4 = *(const float4*)(s+idx+4);
  u8v o;
  o[0]=f2b(a.x);o[1]=f2b(a.y);o[2]=f2b(a.z);o[3]=f2b(a.w);
  o[4]=f2b(b4.x);o[5]=f2b(b4.y);o[6]=f2b(b4.z);o[7]=f2b(b4.w);
  *(u8v*)(wb + ((size_t)which<<20) + idx) = o;
}

// ---------------------------------------------------------------- pack mask -> bitmask (1 bit/entry)
__global__ __launch_bounds__(256) void pack_mask_kernel(
    const int* __restrict__ mask, unsigned char* __restrict__ mbits){
  int t = blockIdx.x*256 + threadIdx.x;       // one byte (8 mask entries) per thread
  const int* src = mask + ((size_t)t<<3);
  int4 a = *(const int4*)src; int4 b = *(const int4*)(src+4);
  unsigned m = (a.x&1) | ((a.y&1)<<1) | ((a.z&1)<<2) | ((a.w&1)<<3)
             | ((b.x&1)<<4) | ((b.y&1)<<5) | ((b.z&1)<<6) | ((b.w&1)<<7);
  mbits[t] = (unsigned char)m;
}

// ---------------------------------------------------------------- shared 128x128 bf16 GEMM body
__device__ __forceinline__ void gemm_body(
    const ushort* __restrict__ A, const ushort* __restrict__ W,
    ushort* __restrict__ outb, float* __restrict__ outf, const float* __restrict__ resid,
    int mode, float scale){
  __shared__ ushort As[4096];   // [128][32]
  __shared__ ushort Bs[4096];   // [128][32] (n-major)
  int tid = threadIdx.x;
  int w = tid>>6, lane = tid&63, lane15 = lane&15, g = lane>>4;
  int m0 = blockIdx.y<<7, n0 = blockIdx.x<<7;
  int wr = w>>1, wc = w&1;
  f4v z4 = {0.f,0.f,0.f,0.f};
  f4v acc[4][4];
  #pragma unroll
  for (int i=0;i<4;++i)
    #pragma unroll
    for (int j=0;j<4;++j) acc[i][j] = z4;

  int f0 = tid, f1 = 256 + tid;
  int r0 = f0>>2, c0 = (f0&3)<<3;
  int r1 = f1>>2, c1 = (f1&3)<<3;
  for (int k0=0; k0<1024; k0+=32){
    *(s8v*)&As[(r0<<5)+c0] = *(const s8v*)&A[((size_t)(m0+r0)<<10) + k0 + c0];
    *(s8v*)&As[(r1<<5)+c1] = *(const s8v*)&A[((size_t)(m0+r1)<<10) + k0 + c1];
    *(s8v*)&Bs[(r0<<5)+c0] = *(const s8v*)&W[((size_t)(n0+r0)<<10) + k0 + c0];
    *(s8v*)&Bs[(r1<<5)+c1] = *(const s8v*)&W[((size_t)(n0+r1)<<10) + k0 + c1];
    __syncthreads();
    s8v af[4], bf_[4];
    #pragma unroll
    for (int mi=0;mi<4;++mi) af[mi] = *(s8v*)&As[((wr*64 + mi*16 + lane15)<<5) + (g<<3)];
    #pragma unroll
    for (int ni=0;ni<4;++ni) bf_[ni] = *(s8v*)&Bs[((wc*64 + ni*16 + lane15)<<5) + (g<<3)];
    #pragma unroll
    for (int mi=0;mi<4;++mi)
      #pragma unroll
      for (int ni=0;ni<4;++ni)
        acc[mi][ni] = __builtin_amdgcn_mfma_f32_16x16x32_bf16(af[mi], bf_[ni], acc[mi][ni], 0,0,0);
    __syncthreads();
  }
  #pragma unroll
  for (int mi=0;mi<4;++mi){
    #pragma unroll
    for (int ni=0;ni<4;++ni){
      int mbase = m0 + wr*64 + mi*16 + (g<<2);
      int ncol  = n0 + wc*64 + ni*16 + lane15;
      if (mode==0){
        int b=mbase>>11, h=ncol>>6, j=ncol&63;
        size_t o = (((size_t)(b*HH+h)*LL + (mbase&2047))<<6) + j;
        #pragma unroll
        for (int r=0;r<4;++r) outb[o + ((size_t)r<<6)] = f2b(acc[mi][ni][r]*scale);
      } else if (mode==2){
        int b=mbase>>11, h=ncol>>6, j=ncol&63;
        ushort4 pk = make_ushort4(f2b(acc[mi][ni][0]), f2b(acc[mi][ni][1]),
                                  f2b(acc[mi][ni][2]), f2b(acc[mi][ni][3]));
        *(ushort4*)&outb[(((size_t)(b*HH+h)*DKk + j)<<11) + (mbase&2047)] = pk;
      } else {
        int b=mbase>>11, l2=mbase&2047;
        #pragma unroll
        for (int r=0;r<4;++r)
          outf[((size_t)(mbase+r)<<10)+ncol] =
              acc[mi][ni][r] + resid[((size_t)((l2+r)*BB + b)<<10) + ncol];
      }
    }
  }
}

__global__ __launch_bounds__(256) void gemm_qkv_kernel(
    const ushort* __restrict__ xq, const ushort* __restrict__ xk, const ushort* __restrict__ xv,
    const ushort* __restrict__ wb, ushort* __restrict__ Qh, ushort* __restrict__ Kh, ushort* __restrict__ Vt){
  int z = blockIdx.z;
  const ushort* A = (z==0)?xq:(z==1)?xk:xv;
  const ushort* W = wb + ((size_t)z<<20);
  ushort* outb = (z==0)?Qh:(z==1)?Kh:Vt;
  int mode = (z==2)?2:0;
  float scale = (z==0)?0.125f:1.0f;
  gemm_body(A, W, outb, nullptr, nullptr, mode, scale);
}

__global__ __launch_bounds__(256) void gemm_fc_kernel(
    const ushort* __restrict__ ao, const ushort* __restrict__ wfc,
    const float* __restrict__ resid, float* __restrict__ fco){
  gemm_body(ao, wfc, nullptr, fco, resid, 3, 1.0f);
}

// ---------------------------------------------------------------- fused attention
// 16 q-rows of one (b,h) per block, 1024 threads (16 waves), 2 blocks/CU.
// S-tile 64KB bf16 LDS, XOR-swizzled (byte ^= (row&7)<<4). No max pass (logits
// bounded); masked entries -> e = 0. All hot loops register-double-buffered.
__global__ __launch_bounds__(1024, 8) void attn_kernel(
    const ushort* __restrict__ Qh, const ushort* __restrict__ Kh, const ushort* __restrict__ Vt,
    const float* __restrict__ sph, const unsigned char* __restrict__ mbits,
    float* __restrict__ p_out, ushort* __restrict__ attn_out){
  extern __shared__ char smem[];            // 65536 S + 13056 partials + 64 redsum
  float* pbuf   = (float*)(smem + 65536);   // [3][16][68-padded]
  float* redsum = (float*)(smem + 65536 + 13056);
  int tid = threadIdx.x, w = tid>>6, lane = tid&63, lane15 = lane&15, g = lane>>4;
  int bid = blockIdx.x;
  int qt = bid & 127, h = (bid>>7)&15, b = bid>>11;
  int q0 = qt<<4;
  size_t bh = (size_t)b*HH + h;

  // ---- P1: S = (Q/8) K^T -> LDS bf16 swizzled. wave w owns col chunks w*8..w*8+7.
  const ushort* Qbase = Qh + ((bh*LL + q0 + lane15)<<6) + (g<<3);
  s8v qa0 = *(const s8v*)Qbase;
  s8v qa1 = *(const s8v*)(Qbase + 32);
  const ushort* Kp = Kh + ((bh*LL + (w<<7) + lane15)<<6) + (g<<3);
  s8v kb0n = *(const s8v*)Kp;
  s8v kb1n = *(const s8v*)(Kp + 32);
  #pragma unroll
  for (int cc=0; cc<8; ++cc){
    s8v kb0 = kb0n, kb1 = kb1n;
    if (cc<7){
      kb0n = *(const s8v*)(Kp + ((cc+1)<<10));
      kb1n = *(const s8v*)(Kp + ((cc+1)<<10) + 32);
    }
    f4v cacc = {0.f,0.f,0.f,0.f};
    cacc = __builtin_amdgcn_mfma_f32_16x16x32_bf16(qa0, kb0, cacc, 0,0,0);
    cacc = __builtin_amdgcn_mfma_f32_16x16x32_bf16(qa1, kb1, cacc, 0,0,0);
    int colb = (((w<<3)+cc)<<5) + (lane15<<1);
    #pragma unroll
    for (int r=0;r<4;++r){
      int row = (g<<2)+r;
      *(ushort*)(smem + (row<<12) + (colb ^ ((row&7)<<4))) = f2b(cacc[r]);
    }
  }
  __syncthreads();

  // ---- P2: wave w owns q-row w. e = mask ? exp(S*sph) : 0 -> LDS bf16; row sum.
  int row = w;
  int qrow = q0 + row;
  const float* sph_r = sph + ((bh*LL + qrow)<<11);
  const unsigned char* mb_r = mbits + (((size_t)b*LL + qrow)<<8);
  int rswz = (row&7)<<4;
  char* Srow = smem + (row<<12);
  int colbase = lane<<3;
  // mask bits for this lane's 4 chunks (1 byte each)
  unsigned mw = (unsigned)mb_r[lane] | ((unsigned)mb_r[lane+64]<<8)
              | ((unsigned)mb_r[lane+128]<<16) | ((unsigned)mb_r[lane+192]<<24);
  f4v a0 = nt4(sph_r + colbase), a1 = nt4(sph_r + colbase + 4);
  s8v svn = *(s8v*)(Srow + ((colbase<<1) ^ rswz));
  float sum = 0.f;
  #pragma unroll
  for (int c2=0;c2<4;++c2){
    f4v p0 = a0, p1 = a1; s8v sv = svn;
    if (c2<3){
      int ncol = colbase + ((c2+1)<<9);
      a0 = nt4(sph_r + ncol); a1 = nt4(sph_r + ncol + 4);
      svn = *(s8v*)(Srow + ((ncol<<1) ^ rswz));
    }
    unsigned m8 = (mw >> (c2*8));
    float e[8];
    e[0] = (m8&1)   ? __expf(b2f((ushort)sv[0])*p0[0]) : 0.f;
    e[1] = (m8&2)   ? __expf(b2f((ushort)sv[1])*p0[1]) : 0.f;
    e[2] = (m8&4)   ? __expf(b2f((ushort)sv[2])*p0[2]) : 0.f;
    e[3] = (m8&8)   ? __expf(b2f((ushort)sv[3])*p0[3]) : 0.f;
    e[4] = (m8&16)  ? __expf(b2f((ushort)sv[4])*p1[0]) : 0.f;
    e[5] = (m8&32)  ? __expf(b2f((ushort)sv[5])*p1[1]) : 0.f;
    e[6] = (m8&64)  ? __expf(b2f((ushort)sv[6])*p1[2]) : 0.f;
    e[7] = (m8&128) ? __expf(b2f((ushort)sv[7])*p1[3]) : 0.f;
    u8v ov;
    #pragma unroll
    for (int j=0;j<8;++j){ sum += e[j]; ov[j] = f2b(e[j]); }
    *(u8v*)(Srow + (((colbase + (c2<<9))<<1) ^ rswz)) = ov;
  }
  #pragma unroll
  for (int off=1; off<64; off<<=1) sum += __shfl_xor(sum, off, 64);
  if (lane==0) redsum[row] = sum;

  // ---- P3: normalized p -> global (nt stores; all 4 ds_reads issued upfront)
  float inv = 1.0f / sum;
  float* prow_p = p_out + ((bh*LL + qrow)<<11);
  s8v rv[4];
  #pragma unroll
  for (int c2=0;c2<4;++c2)
    rv[c2] = *(s8v*)(Srow + (((colbase + (c2<<9))<<1) ^ rswz));
  #pragma unroll
  for (int c2=0;c2<4;++c2){
    int col = colbase + (c2<<9);
    f4v o0, o1;
    o0[0]=b2f((ushort)rv[c2][0])*inv; o0[1]=b2f((ushort)rv[c2][1])*inv;
    o0[2]=b2f((ushort)rv[c2][2])*inv; o0[3]=b2f((ushort)rv[c2][3])*inv;
    o1[0]=b2f((ushort)rv[c2][4])*inv; o1[1]=b2f((ushort)rv[c2][5])*inv;
    o1[2]=b2f((ushort)rv[c2][6])*inv; o1[3]=b2f((ushort)rv[c2][7])*inv;
    nts4(prow_p + col, o0);
    nts4(prow_p + col + 4, o1);
  }
  __syncthreads();

  // ---- P4: O = (e V)/sum. wave w: d-slice ds=w&3, k-quarter kq=w>>2 (512 k each).
  int ds = w & 3, kq = w >> 2;
  f4v oacc = {0.f,0.f,0.f,0.f};
  const ushort* Vb = Vt + ((bh*DKk + (ds<<4) + lane15)<<11) + (kq<<9) + (g<<3);
  char* Sa = smem + (lane15<<12);
  int aswz = (lane15&7)<<4;
  s8v pan = *(s8v*)(Sa + (((kq<<10) + (g<<4)) ^ aswz));
  s8v vbn = *(const s8v*)Vb;
  #pragma unroll
  for (int it=0; it<16; ++it){
    s8v pa = pan, vb = vbn;
    if (it<15){
      pan = *(s8v*)(Sa + (((kq<<10) + ((it+1)<<6) + (g<<4)) ^ aswz));
      vbn = *(const s8v*)(Vb + ((it+1)<<5));
    }
    oacc = __builtin_amdgcn_mfma_f32_16x16x32_bf16(pa, vb, oacc, 0,0,0);
  }
  if (kq){
    float* pp = pbuf + ((kq-1)*1088);
    #pragma unroll
    for (int r=0;r<4;++r) pp[((g<<2)+r)*68 + (ds<<4) + lane15] = oacc[r];
  }
  __syncthreads();
  if (kq==0){
    #pragma unroll
    for (int p=0;p<3;++p){
      float* pp = pbuf + p*1088;
      #pragma unroll
      for (int r=0;r<4;++r) oacc[r] += pp[((g<<2)+r)*68 + (ds<<4) + lane15];
    }
    #pragma unroll
    for (int r=0;r<4;++r){
      int qr = (g<<2)+r;
      float val = oacc[r] / redsum[qr];
      attn_out[((size_t)(b*LL + q0 + qr)<<10) + (h<<6) + (ds<<4) + lane15] = f2b(val);
    }
  }
}

// ---------------------------------------------------------------- LayerNorm + final transpose
__global__ __launch_bounds__(256) void ln_kernel(const float* __restrict__ fc,
    const float* __restrict__ gamma, const float* __restrict__ beta, float* __restrict__ out){
  __shared__ float rs[4], rq[4];
  int m = blockIdx.x, tid = threadIdx.x;
  int d0 = tid<<2;
  float4 x = *(const float4*)(fc + ((size_t)m<<10) + d0);
  float s = x.x+x.y+x.z+x.w;
  float sq = x.x*x.x+x.y*x.y+x.z*x.z+x.w*x.w;
  #pragma unroll
  for (int off=32; off; off>>=1){ s += __shfl_xor(s,off,64); sq += __shfl_xor(sq,off,64); }
  if ((tid&63)==0){ rs[tid>>6]=s; rq[tid>>6]=sq; }
  __syncthreads();
  float ts = rs[0]+rs[1]+rs[2]+rs[3];
  float tq = rq[0]+rq[1]+rq[2]+rq[3];
  float mu = ts*(1.0f/1024.0f);
  float var = tq*(1.0f/1024.0f) - mu*mu;
  float rr = rsqrtf(var + 1e-6f);
  float4 gm = *(const float4*)(gamma + d0);
  float4 bt = *(const float4*)(beta + d0);
  float4 y;
  y.x=(x.x-mu)*rr*gm.x+bt.x;
  y.y=(x.y-mu)*rr*gm.y+bt.y;
  y.z=(x.z-mu)*rr*gm.z+bt.z;
  y.w=(x.w-mu)*rr*gm.w+bt.w;
  int b=m>>11, l2=m&2047;
  *(float4*)(out + ((size_t)(l2*BB+b)<<10) + d0) = y;
}

// ---------------------------------------------------------------- launch
extern "C" void kernel_launch(void* const* d_in, const int* in_sizes, int n_in,
                              void* d_out, int out_size, void* d_ws, size_t ws_size,
                              hipStream_t stream){
  const float* q    = (const float*)d_in[0];
  const float* k    = (const float*)d_in[1];
  const float* v    = (const float*)d_in[2];
  const float* sph  = (const float*)d_in[3];
  const int*   mask = (const int*)d_in[4];
  const float* Wq   = (const float*)d_in[5];
  const float* Wk   = (const float*)d_in[6];
  const float* Wv   = (const float*)d_in[7];
  const float* Wfc  = (const float*)d_in[8];
  const float* gamma= (const float*)d_in[9];
  const float* beta = (const float*)d_in[10];
  float* outp  = (float*)d_out;
  float* p_out = outp + 4194304;            // L*B*D floats, then p_attn

  char* ws = (char*)d_ws;
  ushort* xq  = (ushort*)(ws);
  ushort* xk  = (ushort*)(ws + 8388608);
  ushort* xv  = (ushort*)(ws + 16777216);
  ushort* wb  = (ushort*)(ws + 25165824);   // 4 x 2MB bf16 weights
  ushort* Qh  = (ushort*)(ws + 33554432);
  ushort* Kh  = (ushort*)(ws + 41943040);
  ushort* Vt  = (ushort*)(ws + 50331648);
  ushort* ao  = (ushort*)(ws + 58720256);   // attn merged-head out bf16 [4096][1024]
  float*  fco = (float*)(ws + 67108864);    // fc + residual fp32 [4096][1024]
  unsigned char* mbits = (unsigned char*)(ws + 83886080);  // 1MB bitmask

  pack_x_kernel<<<2048,256,0,stream>>>(q,k,v,xq,xk,xv);
  pack_w_kernel<<<2048,256,0,stream>>>(Wq,Wk,Wv,Wfc,wb);
  pack_mask_kernel<<<4096,256,0,stream>>>(mask, mbits);
  gemm_qkv_kernel<<<dim3(8,32,3),256,0,stream>>>(xq,xk,xv,wb,Qh,Kh,Vt);
  attn_kernel<<<4096,1024,78784,stream>>>(Qh,Kh,Vt,sph,mbits,p_out,ao);
  gemm_fc_kernel<<<dim3(8,32),256,0,stream>>>(ao, wb + 3145728, q, fco);
  ln_kernel<<<4096,256,0,stream>>>(fco, gamma, beta, outp);
}